// Round 9
// baseline (53.934 us; speedup 1.0000x reference)
//
#include <hip/hip_runtime.h>

// Quadrilinear upsample, align_corners=True.
// in : [1, 16, 5, 5, 128, 128] f32 -> out: [1, 16, 8, 8, 256, 256] f32
//
// R9: R8 byte-identical except PLAIN stores (A/B #2 on store policy).
// R5's plain-store loss was measured at the R4 structure (285 MB of L2 read
// traffic to thrash); R8 reads only 82 MB total, so plain writes can now use
// L2 write-staging (the fill kernel's 7 TB/s path) without evicting reads.

constexpr int C  = 16;
constexpr int IX = 5,  IY = 5,  IU = 128, IV = 128;
constexpr int OX = 8,  OY = 8,  OU = 256, OV = 256;
constexpr int QROWS = 16;          // output U rows per slice
constexpr int SROWS = 10;          // staged input U rows per slice
constexpr int PLANE = SROWS * IV;  // 1280 floats per blended plane
constexpr int NQ    = OU / QROWS;  // 16 u-slices

typedef float floatx4 __attribute__((ext_vector_type(4)));

__global__ __launch_bounds__(256) void interp4d(const float* __restrict__ in,
                                                float* __restrict__ out) {
    __shared__ float lds[4 * PLANE];   // 20,480 B exactly -> 8 blocks/CU

    const int b  = blockIdx.x;
    const int q  = b & (NQ - 1);     // u-slice
    const int yp = (b >> 4) & 3;     // yo-pair
    const int xp = (b >> 6) & 3;     // xo-pair
    const int c  = b >> 8;

    const float sxy = 4.0f / 7.0f;
    const float suv = 127.0f / 255.0f;

    float ax[2]; int xp0;
    {
        float cx = (float)(2 * xp) * sxy;
        int x0 = (int)cx; x0 = x0 > IX - 1 ? IX - 1 : x0;
        xp0 = x0; ax[0] = cx - (float)x0;
        cx = (float)(2 * xp + 1) * sxy;
        x0 = (int)cx; x0 = x0 > IX - 1 ? IX - 1 : x0;
        ax[1] = (x0 > xp0) ? 1.0f : (cx - (float)x0);
    }
    const int xp1 = xp0 + 1 < IX ? xp0 + 1 : IX - 1;

    float ay[2]; int yp0;
    {
        float cy = (float)(2 * yp) * sxy;
        int y0 = (int)cy; y0 = y0 > IY - 1 ? IY - 1 : y0;
        yp0 = y0; ay[0] = cy - (float)y0;
        cy = (float)(2 * yp + 1) * sxy;
        y0 = (int)cy; y0 = y0 > IY - 1 ? IY - 1 : y0;
        ay[1] = (y0 > yp0) ? 1.0f : (cy - (float)y0);
    }
    const int yp1 = yp0 + 1 < IY ? yp0 + 1 : IY - 1;

    const int ubase = (int)((float)(q * QROWS) * suv);   // first staged row

    const size_t psz = (size_t)IU * IV;
    const floatx4* p00 = (const floatx4*)(in + ((size_t)(c * IX + xp0) * IY + yp0) * psz);
    const floatx4* p01 = (const floatx4*)(in + ((size_t)(c * IX + xp0) * IY + yp1) * psz);
    const floatx4* p10 = (const floatx4*)(in + ((size_t)(c * IX + xp1) * IY + yp0) * psz);
    const floatx4* p11 = (const floatx4*)(in + ((size_t)(c * IX + xp1) * IY + yp1) * psz);

    // Stage: read 4 raw corner slices once, emit 4 xy-blended planes.
    floatx4* lp = (floatx4*)lds;
    for (int i = threadIdx.x; i < SROWS * (IV / 4); i += 256) {
        int r  = i >> 5;
        int gr = ubase + r; gr = gr > IU - 1 ? IU - 1 : gr;
        int gi = gr * (IV / 4) + (i & 31);
        floatx4 a00 = p00[gi], a01 = p01[gi], a10 = p10[gi], a11 = p11[gi];
#pragma unroll
        for (int dy = 0; dy < 2; ++dy) {
            floatx4 q0 = a00 + (a01 - a00) * ay[dy];
            floatx4 q1 = a10 + (a11 - a10) * ay[dy];
#pragma unroll
            for (int dx = 0; dx < 2; ++dx) {
                lp[(dx * 2 + dy) * (PLANE / 4) + i] = q0 + (q1 - q0) * ax[dx];
            }
        }
    }
    __syncthreads();

    const int lane = threadIdx.x & 63;
    const int wg   = threadIdx.x >> 6;

    // Per-lane V setup: outputs vo=4*lane+j need elements [a_ .. a_+3] only.
    int a_; float vw0, vw1, vw2, vw3; int s1, s2, s3;
    {
        float cv = (float)(4 * lane) * suv;
        int v0 = (int)cv; v0 = v0 > IV - 1 ? IV - 1 : v0;
        a_ = v0; vw0 = cv - (float)v0;
        cv = (float)(4 * lane + 1) * suv;
        v0 = (int)cv; v0 = v0 > IV - 1 ? IV - 1 : v0;
        s1 = v0 - a_; vw1 = cv - (float)v0;
        cv = (float)(4 * lane + 2) * suv;
        v0 = (int)cv; v0 = v0 > IV - 1 ? IV - 1 : v0;
        s2 = v0 - a_; vw2 = cv - (float)v0;
        cv = (float)(4 * lane + 3) * suv;
        v0 = (int)cv; v0 = v0 > IV - 1 ? IV - 1 : v0;
        s3 = v0 - a_; vw3 = cv - (float)v0;
    }
    const bool c1a = (s1 == 0), c1b = (s1 == 1);
    const bool c2a = (s2 == 0), c2b = (s2 == 1);
    const bool c3a = (s3 == 0), c3b = (s3 == 1);

    float* ob[4];
#pragma unroll
    for (int m = 0; m < 4; ++m) {
        int xo = 2 * xp + (m >> 1), yo = 2 * yp + (m & 1);
        ob[m] = out + (((size_t)(c * OX + xo) * OY + yo) * OU + q * QROWS) * OV;
    }

    for (int ul = wg; ul < QROWS; ul += 4) {
        int   uo = q * QROWS + ul;
        float cu = (float)uo * suv;
        int   u0 = (int)cu; u0 = u0 > IU - 1 ? IU - 1 : u0;
        int   u1 = u0 + 1 < IU ? u0 + 1 : IU - 1;
        float wu = cu - (float)u0;
        const int lr0 = (u0 - ubase) * IV + a_;
        const int lr1 = (u1 - ubase) * IV + a_;
#pragma unroll
        for (int m = 0; m < 4; ++m) {
            const float* r0 = lds + m * PLANE + lr0;
            const float* r1 = lds + m * PLANE + lr1;
            float f0 = r0[0], f1 = r0[1], f2 = r0[2], f3 = r0[3];
            float h0 = r1[0], h1 = r1[1], h2 = r1[2], h3 = r1[3];
            float g0 = f0 + (h0 - f0) * wu;
            float g1 = f1 + (h1 - f1) * wu;
            float g2 = f2 + (h2 - f2) * wu;
            float g3 = f3 + (h3 - f3) * wu;
            float x01 = c1a ? g0 : (c1b ? g1 : g2);
            float x11 = c1a ? g1 : (c1b ? g2 : g3);
            float x02 = c2a ? g0 : (c2b ? g1 : g2);
            float x12 = c2a ? g1 : (c2b ? g2 : g3);
            float x03 = c3a ? g0 : (c3b ? g1 : g2);
            float x13 = c3a ? g1 : (c3b ? g2 : g3);
            floatx4 res;
            res.x = g0  + (g1  - g0 ) * vw0;
            res.y = x01 + (x11 - x01) * vw1;
            res.z = x02 + (x12 - x02) * vw2;
            res.w = x03 + (x13 - x03) * vw3;
            ((floatx4*)(ob[m] + (size_t)ul * OV))[lane] = res;  // PLAIN store (A/B vs nt @ full occ)
        }
    }
}

extern "C" void kernel_launch(void* const* d_in, const int* in_sizes, int n_in,
                              void* d_out, int out_size, void* d_ws, size_t ws_size,
                              hipStream_t stream) {
    const float* in  = (const float*)d_in[0];
    float*       out = (float*)d_out;
    interp4d<<<dim3(C * 4 * 4 * NQ), dim3(256), 0, stream>>>(in, out);
}

// Round 10
// 52.522 us; speedup vs baseline: 1.0269x; 1.0269x over previous
//
#include <hip/hip_runtime.h>

// Quadrilinear upsample, align_corners=True.
// in : [1, 16, 5, 5, 128, 128] f32 -> out: [1, 16, 8, 8, 256, 256] f32
//
// FINAL (= R7, best measured 52.7 us): block = (c, xp, yp, u-slice of 16 rows).
// 4 xy-blended planes shared per block (20 KB LDS, 7-8 blocks/CU), deduped
// 8-read inner loop, nontemporal dwordx4 stores.
// Roofline: 294 MB mixed r+w in ~53 us = 5.6 TB/s = 89% of the 6.29 TB/s
// measured copy ceiling. A/B-verified neutral: occupancy beyond 4 blk/CU,
// L2 read traffic 4x, nt-vs-plain stores (at full occ), store sequencing.

constexpr int C  = 16;
constexpr int IX = 5,  IY = 5,  IU = 128, IV = 128;
constexpr int OX = 8,  OY = 8,  OU = 256, OV = 256;
constexpr int QROWS = 16;          // output U rows per slice
constexpr int SROWS = 10;          // staged input U rows per slice
constexpr int PLANE = SROWS * IV;  // 1280 floats per blended plane
constexpr int NQ    = OU / QROWS;  // 16 u-slices

typedef float floatx4 __attribute__((ext_vector_type(4)));

__global__ __launch_bounds__(256) void interp4d(const float* __restrict__ in,
                                                float* __restrict__ out) {
    __shared__ float lds[4 * PLANE + 4];   // 4 blended planes + zero pad

    const int b  = blockIdx.x;
    const int q  = b & (NQ - 1);     // u-slice
    const int yp = (b >> 4) & 3;     // yo-pair
    const int xp = (b >> 6) & 3;     // xo-pair
    const int c  = b >> 8;

    const float sxy = 4.0f / 7.0f;
    const float suv = 127.0f / 255.0f;

    float ax[2]; int xp0;
    {
        float cx = (float)(2 * xp) * sxy;
        int x0 = (int)cx; x0 = x0 > IX - 1 ? IX - 1 : x0;
        xp0 = x0; ax[0] = cx - (float)x0;
        cx = (float)(2 * xp + 1) * sxy;
        x0 = (int)cx; x0 = x0 > IX - 1 ? IX - 1 : x0;
        ax[1] = (x0 > xp0) ? 1.0f : (cx - (float)x0);
    }
    const int xp1 = xp0 + 1 < IX ? xp0 + 1 : IX - 1;

    float ay[2]; int yp0;
    {
        float cy = (float)(2 * yp) * sxy;
        int y0 = (int)cy; y0 = y0 > IY - 1 ? IY - 1 : y0;
        yp0 = y0; ay[0] = cy - (float)y0;
        cy = (float)(2 * yp + 1) * sxy;
        y0 = (int)cy; y0 = y0 > IY - 1 ? IY - 1 : y0;
        ay[1] = (y0 > yp0) ? 1.0f : (cy - (float)y0);
    }
    const int yp1 = yp0 + 1 < IY ? yp0 + 1 : IY - 1;

    const int ubase = (int)((float)(q * QROWS) * suv);   // first staged row

    const size_t psz = (size_t)IU * IV;
    const floatx4* p00 = (const floatx4*)(in + ((size_t)(c * IX + xp0) * IY + yp0) * psz);
    const floatx4* p01 = (const floatx4*)(in + ((size_t)(c * IX + xp0) * IY + yp1) * psz);
    const floatx4* p10 = (const floatx4*)(in + ((size_t)(c * IX + xp1) * IY + yp0) * psz);
    const floatx4* p11 = (const floatx4*)(in + ((size_t)(c * IX + xp1) * IY + yp1) * psz);

    if (threadIdx.x < 4) lds[4 * PLANE + threadIdx.x] = 0.0f;

    // Stage: read 4 raw corner slices once, emit 4 xy-blended planes.
    floatx4* lp = (floatx4*)lds;
    for (int i = threadIdx.x; i < SROWS * (IV / 4); i += 256) {
        int r  = i >> 5;
        int gr = ubase + r; gr = gr > IU - 1 ? IU - 1 : gr;
        int gi = gr * (IV / 4) + (i & 31);
        floatx4 a00 = p00[gi], a01 = p01[gi], a10 = p10[gi], a11 = p11[gi];
#pragma unroll
        for (int dy = 0; dy < 2; ++dy) {
            floatx4 q0 = a00 + (a01 - a00) * ay[dy];
            floatx4 q1 = a10 + (a11 - a10) * ay[dy];
#pragma unroll
            for (int dx = 0; dx < 2; ++dx) {
                lp[(dx * 2 + dy) * (PLANE / 4) + i] = q0 + (q1 - q0) * ax[dx];
            }
        }
    }
    __syncthreads();

    const int lane = threadIdx.x & 63;
    const int wg   = threadIdx.x >> 6;

    // Per-lane V setup: outputs vo=4*lane+j need elements [a_ .. a_+3] only.
    int a_; float vw0, vw1, vw2, vw3; int s1, s2, s3;
    {
        float cv = (float)(4 * lane) * suv;
        int v0 = (int)cv; v0 = v0 > IV - 1 ? IV - 1 : v0;
        a_ = v0; vw0 = cv - (float)v0;
        cv = (float)(4 * lane + 1) * suv;
        v0 = (int)cv; v0 = v0 > IV - 1 ? IV - 1 : v0;
        s1 = v0 - a_; vw1 = cv - (float)v0;
        cv = (float)(4 * lane + 2) * suv;
        v0 = (int)cv; v0 = v0 > IV - 1 ? IV - 1 : v0;
        s2 = v0 - a_; vw2 = cv - (float)v0;
        cv = (float)(4 * lane + 3) * suv;
        v0 = (int)cv; v0 = v0 > IV - 1 ? IV - 1 : v0;
        s3 = v0 - a_; vw3 = cv - (float)v0;
    }
    const bool c1a = (s1 == 0), c1b = (s1 == 1);
    const bool c2a = (s2 == 0), c2b = (s2 == 1);
    const bool c3a = (s3 == 0), c3b = (s3 == 1);

    float* ob[4];
#pragma unroll
    for (int m = 0; m < 4; ++m) {
        int xo = 2 * xp + (m >> 1), yo = 2 * yp + (m & 1);
        ob[m] = out + (((size_t)(c * OX + xo) * OY + yo) * OU + q * QROWS) * OV;
    }

    for (int ul = wg; ul < QROWS; ul += 4) {
        int   uo = q * QROWS + ul;
        float cu = (float)uo * suv;
        int   u0 = (int)cu; u0 = u0 > IU - 1 ? IU - 1 : u0;
        int   u1 = u0 + 1 < IU ? u0 + 1 : IU - 1;
        float wu = cu - (float)u0;
        const int lr0 = (u0 - ubase) * IV + a_;
        const int lr1 = (u1 - ubase) * IV + a_;
#pragma unroll
        for (int m = 0; m < 4; ++m) {
            const float* r0 = lds + m * PLANE + lr0;
            const float* r1 = lds + m * PLANE + lr1;
            float f0 = r0[0], f1 = r0[1], f2 = r0[2], f3 = r0[3];
            float h0 = r1[0], h1 = r1[1], h2 = r1[2], h3 = r1[3];
            float g0 = f0 + (h0 - f0) * wu;
            float g1 = f1 + (h1 - f1) * wu;
            float g2 = f2 + (h2 - f2) * wu;
            float g3 = f3 + (h3 - f3) * wu;
            float x01 = c1a ? g0 : (c1b ? g1 : g2);
            float x11 = c1a ? g1 : (c1b ? g2 : g3);
            float x02 = c2a ? g0 : (c2b ? g1 : g2);
            float x12 = c2a ? g1 : (c2b ? g2 : g3);
            float x03 = c3a ? g0 : (c3b ? g1 : g2);
            float x13 = c3a ? g1 : (c3b ? g2 : g3);
            floatx4 res;
            res.x = g0  + (g1  - g0 ) * vw0;
            res.y = x01 + (x11 - x01) * vw1;
            res.z = x02 + (x12 - x02) * vw2;
            res.w = x03 + (x13 - x03) * vw3;
            __builtin_nontemporal_store(res, (floatx4*)(ob[m] + (size_t)ul * OV) + lane);
        }
    }
}

extern "C" void kernel_launch(void* const* d_in, const int* in_sizes, int n_in,
                              void* d_out, int out_size, void* d_ws, size_t ws_size,
                              hipStream_t stream) {
    const float* in  = (const float*)d_in[0];
    float*       out = (float*)d_out;
    interp4d<<<dim3(C * 4 * 4 * NQ), dim3(256), 0, stream>>>(in, out);
}